// Round 7
// baseline (801.899 us; speedup 1.0000x reference)
//
#include <hip/hip_runtime.h>

// N=32768 rows, K=8192 codes, D=256, fp32 in, int32 out.
constexpr int D_DIM   = 256;
constexpr int N_ROWS  = 32768;
constexpr int K_CODES = 8192;

typedef _Float16 f16x8  __attribute__((ext_vector_type(8)));
typedef __fp16   fp16x2 __attribute__((ext_vector_type(2)));
typedef float    f32x16 __attribute__((ext_vector_type(16)));

#define MFMA32(a, b, c) __builtin_amdgcn_mfma_f32_32x32x16_f16(a, b, c, 0, 0, 0)

// Split one granule (8 fp32) into fp16 hi (pkrtz, RTZ) + fp16 lo (residual).
__device__ __forceinline__ void cvt_granule(const float4 a, const float4 b,
                                            uint4& hi, uint4& lo) {
    fp16x2 h0 = __builtin_amdgcn_cvt_pkrtz(a.x, a.y);
    fp16x2 h1 = __builtin_amdgcn_cvt_pkrtz(a.z, a.w);
    fp16x2 h2 = __builtin_amdgcn_cvt_pkrtz(b.x, b.y);
    fp16x2 h3 = __builtin_amdgcn_cvt_pkrtz(b.z, b.w);
    fp16x2 l0 = __builtin_amdgcn_cvt_pkrtz(a.x - (float)h0.x, a.y - (float)h0.y);
    fp16x2 l1 = __builtin_amdgcn_cvt_pkrtz(a.z - (float)h1.x, a.w - (float)h1.y);
    fp16x2 l2 = __builtin_amdgcn_cvt_pkrtz(b.x - (float)h2.x, b.y - (float)h2.y);
    fp16x2 l3 = __builtin_amdgcn_cvt_pkrtz(b.z - (float)h3.x, b.w - (float)h3.y);
    hi = make_uint4(__builtin_bit_cast(unsigned, h0), __builtin_bit_cast(unsigned, h1),
                    __builtin_bit_cast(unsigned, h2), __builtin_bit_cast(unsigned, h3));
    lo = make_uint4(__builtin_bit_cast(unsigned, l0), __builtin_bit_cast(unsigned, l1),
                    __builtin_bit_cast(unsigned, l2), __builtin_bit_cast(unsigned, l3));
}

// async global->LDS, 16 B per lane; lds dst is wave-uniform base + lane*16.
__device__ __forceinline__ void gl_lds16(const uint4* g, uint4* l) {
    __builtin_amdgcn_global_load_lds(
        (const __attribute__((address_space(1))) void*)g,
        (__attribute__((address_space(3))) void*)l, 16, 0, 0);
}

// ---------------------------------------------------------------------------
// Fused prep (one launch):
//  blocks [0,256)   : split X into blocked hi/lo, 64-row blocks:
//                     granule g = rb*2048 + L*64 + r   (L = d/8, r = row in block)
//  blocks [256,320) : split E into blocked hi/lo, 256-code tiles:
//                     granule g = cb*8192 + L*256 + c
//  blocks [320,2368): esqb[k] = ||e_k||^2 + 1024
// ---------------------------------------------------------------------------
__global__ __launch_bounds__(256)
void prep_kernel(const float* __restrict__ X, const float* __restrict__ E,
                 uint4* __restrict__ Xh, uint4* __restrict__ Xl,
                 uint4* __restrict__ Eh, uint4* __restrict__ El,
                 float* __restrict__ esqb) {
    const int tid = threadIdx.x;
    const int bid = blockIdx.x;
    if (bid < 256) {
#pragma unroll 1
        for (int it = 0; it < 16; ++it) {
            const int g = bid * 4096 + it * 256 + tid;
            const int rb = g >> 11, rem = g & 2047;
            const int L = rem >> 6, r = rem & 63;
            const float* p = X + (size_t)(rb * 64 + r) * D_DIM + L * 8;
            const float4 a = *(const float4*)p, b = *(const float4*)(p + 4);
            uint4 hi, lo; cvt_granule(a, b, hi, lo);
            Xh[g] = hi; Xl[g] = lo;
        }
    } else if (bid < 320) {
        const int cbk = bid - 256;
#pragma unroll 1
        for (int it = 0; it < 16; ++it) {
            const int g = cbk * 4096 + it * 256 + tid;
            const int cb = g >> 13, rem = g & 8191;
            const int L = rem >> 8, c = rem & 255;
            const float* p = E + (size_t)(cb * 256 + c) * D_DIM + L * 8;
            const float4 a = *(const float4*)p, b = *(const float4*)(p + 4);
            uint4 hi, lo; cvt_granule(a, b, hi, lo);
            Eh[g] = hi; El[g] = lo;
        }
    } else {
        const int t = (bid - 320) * 256 + tid;
        const int gw = t >> 6, lane = t & 63;
        const float4 v = ((const float4*)(E + (size_t)gw * D_DIM))[lane];
        float s = v.x * v.x + v.y * v.y + v.z * v.z + v.w * v.w;
#pragma unroll
        for (int off = 32; off; off >>= 1) s += __shfl_down(s, off, 64);
        if (lane == 0) esqb[gw] = s + 1024.0f;
    }
}

// ---------------------------------------------------------------------------
// Main: barrier-free K-loop. Block = 64 rows (X hi/lo resident in LDS, staged
// ONCE). Each of 4 waves owns a disjoint 128-code strip per 512-code pass and
// loads its E fragments DIRECTLY global->VGPR (coalesced: frag = 16 B/lane,
// contiguous per half-wave). Per K-step: 8 global_load_dwordx4 + 4
// ds_read_b128 + 24 MFMA, no __syncthreads -> compiler free to pipeline with
// fine-grained vmcnt (the AITER/hipBLASLt pattern). Per-pass argmin folds via
// 32-lane butterfly into wave-private LDS slots; final cross-wave combine
// writes out[] directly (block covers all K; no atomics).
// ---------------------------------------------------------------------------
__global__ __launch_bounds__(256, 2)
void vq_mfma4_kernel(const uint4* __restrict__ Xh, const uint4* __restrict__ Xl,
                     const uint4* __restrict__ Eh, const uint4* __restrict__ El,
                     const float* __restrict__ esqb, int* __restrict__ out) {
    __shared__ uint4 sXh[2048], sXl[2048];   // 64 KB: X block hi/lo, whole D
    __shared__ float swb[4 * 64];
    __shared__ int   swi[4 * 64];

    const int tid  = threadIdx.x;
    const int lane = tid & 63;
    const int wv   = tid >> 6;
    const int l31  = lane & 31;
    const int lh   = lane >> 5;
    const int wbase = wv << 6;
    const int bx   = blockIdx.x;

    const uint4* Xhb = Xh + bx * 2048;
    const uint4* Xlb = Xl + bx * 2048;

    // ---- one-time X stage (async, drained by the single barrier below) ----
#pragma unroll
    for (int i = 0; i < 8; ++i) gl_lds16(Xhb + i * 256 + tid, &sXh[i * 256 + wbase]);
#pragma unroll
    for (int i = 0; i < 8; ++i) gl_lds16(Xlb + i * 256 + tid, &sXl[i * 256 + wbase]);

    swb[wv * 64 + lane] = 3.0e38f;
    swi[wv * 64 + lane] = 0;
    __syncthreads();

    f32x16 acc[2][4];

#pragma unroll 1
    for (int p = 0; p < 16; ++p) {           // 16 passes of 512 codes
        const int cb    = p * 2 + (wv >> 1); // 256-code tile for this wave
        const int coff  = (wv & 1) * 128;    // offset within tile
        const size_t eb0 = (size_t)cb * 8192 + (size_t)lh * 256 + coff + l31;
        const uint4* Ehp = Eh + eb0;
        const uint4* Elp = El + eb0;

#pragma unroll
        for (int ti = 0; ti < 2; ++ti)
#pragma unroll
            for (int tj = 0; tj < 4; ++tj)
#pragma unroll
                for (int i = 0; i < 16; ++i) acc[ti][tj][i] = 0.0f;

#pragma unroll
        for (int s = 0; s < 16; ++s) {       // K-steps of 16 dims
            f16x8 b0[4], b1[4], a0[2], a1[2];
#pragma unroll
            for (int tj = 0; tj < 4; ++tj) {
                b0[tj] = __builtin_bit_cast(f16x8, Ehp[s * 512 + tj * 32]);
                b1[tj] = __builtin_bit_cast(f16x8, Elp[s * 512 + tj * 32]);
            }
#pragma unroll
            for (int ti = 0; ti < 2; ++ti) {
                const int o = s * 128 + lh * 64 + ti * 32 + l31;
                a0[ti] = __builtin_bit_cast(f16x8, sXh[o]);
                a1[ti] = __builtin_bit_cast(f16x8, sXl[o]);
            }
#pragma unroll
            for (int ti = 0; ti < 2; ++ti)
#pragma unroll
                for (int tj = 0; tj < 4; ++tj)
                    acc[ti][tj] = MFMA32(a1[ti], b0[tj], acc[ti][tj]);   // xl*eh
#pragma unroll
            for (int ti = 0; ti < 2; ++ti)
#pragma unroll
                for (int tj = 0; tj < 4; ++tj)
                    acc[ti][tj] = MFMA32(a0[ti], b1[tj], acc[ti][tj]);   // xh*el
#pragma unroll
            for (int ti = 0; ti < 2; ++ti)
#pragma unroll
                for (int tj = 0; tj < 4; ++tj)
                    acc[ti][tj] = MFMA32(a0[ti], b0[tj], acc[ti][tj]);   // xh*eh
        }

        // ---- per-pass epilogue: fold 4 tj candidates, 32-lane butterfly,
        //      update wave-private LDS running min (codes ascending) ----
        const int code0 = p * 512 + wv * 128;
        float ebv[4];
#pragma unroll
        for (int tj = 0; tj < 4; ++tj) ebv[tj] = esqb[code0 + tj * 32 + l31];
#pragma unroll
        for (int ti = 0; ti < 2; ++ti)
#pragma unroll
            for (int r = 0; r < 16; ++r) {
                float bv = 3.0e38f; int bi = 0;
#pragma unroll
                for (int tj = 0; tj < 4; ++tj) {
                    const float dv = fmaf(-2.0f, acc[ti][tj][r], ebv[tj]);
                    const int code = code0 + tj * 32 + l31;
                    if (dv < bv) { bv = dv; bi = code; }
                }
#pragma unroll
                for (int m = 16; m >= 1; m >>= 1) {
                    const float ov = __shfl_xor(bv, m, 32);
                    const int   oi = __shfl_xor(bi, m, 32);
                    if (ov < bv || (ov == bv && oi < bi)) { bv = ov; bi = oi; }
                }
                if (l31 == 0) {
                    const int row  = ti * 32 + (r & 3) + 8 * (r >> 2) + 4 * lh;
                    const int slot = wv * 64 + row;
                    const float cur = swb[slot];
                    if (bv < cur || (bv == cur && bi < swi[slot])) {
                        swb[slot] = bv; swi[slot] = bi;
                    }
                }
            }
    }

    // ---- combine the 4 waves' per-row results, write final indices ----
    __syncthreads();
    if (tid < 64) {
        float bv = swb[tid]; int bi = swi[tid];
#pragma unroll
        for (int w = 1; w < 4; ++w) {
            const float ov = swb[w * 64 + tid];
            const int   oi = swi[w * 64 + tid];
            if (ov < bv || (ov == bv && oi < bi)) { bv = ov; bi = oi; }
        }
        out[bx * 64 + tid] = bi;
    }
}

// ---------------------------------------------------------------------------
// Fallback (round-4 verified kernel): in-loop split, for small ws_size.
// ---------------------------------------------------------------------------
__global__ void prologue_fb(const float* __restrict__ E, float* __restrict__ esqb,
                            unsigned long long* __restrict__ packed) {
    const int t = blockIdx.x * 256 + threadIdx.x;
    if (t < N_ROWS) packed[t] = ~0ull;
    const int gw = t >> 6, lane = t & 63;
    const float4 v = ((const float4*)(E + (size_t)gw * D_DIM))[lane];
    float s = v.x * v.x + v.y * v.y + v.z * v.z + v.w * v.w;
#pragma unroll
    for (int off = 32; off; off >>= 1) s += __shfl_down(s, off, 64);
    if (lane == 0) esqb[gw] = s + 1024.0f;
}

__global__ __launch_bounds__(256, 2)
void vq_mfma_fallback(const float* __restrict__ X, const float* __restrict__ E,
                      const float* __restrict__ esqb,
                      unsigned long long* __restrict__ packed) {
    __shared__ uint4 fXh[128 * 8], fXl[128 * 8];
    __shared__ uint4 fEh[128 * 8], fEl[128 * 8];
    __shared__ float fEsq[2048];

    const int tid  = threadIdx.x;
    const int lane = tid & 63;
    const int wv   = tid >> 6;
    const int wr   = wv >> 1, wc = wv & 1;
    const int l31  = lane & 31;
    const int lh   = lane >> 5;
    const int row0 = blockIdx.x * 128;
    const int cs0  = blockIdx.y * 2048;

#pragma unroll
    for (int i = 0; i < 8; ++i) fEsq[tid + 256 * i] = esqb[cs0 + tid + 256 * i];

    const int sr = tid >> 3, sg = tid & 7;

    float best[2][16]; int bidx[2][16];
#pragma unroll
    for (int ti = 0; ti < 2; ++ti)
#pragma unroll
        for (int r = 0; r < 16; ++r) { best[ti][r] = 3.0e38f; bidx[ti][r] = 0; }

    f32x16 acc[2][2];

#pragma unroll 1
    for (int ct = 0; ct < 16; ++ct) {
#pragma unroll
        for (int ti = 0; ti < 2; ++ti)
#pragma unroll
            for (int tj = 0; tj < 2; ++tj)
#pragma unroll
                for (int i = 0; i < 16; ++i) acc[ti][tj][i] = 0.0f;

#pragma unroll 1
        for (int dc = 0; dc < 4; ++dc) {
            __syncthreads();
#pragma unroll
            for (int i = 0; i < 4; ++i) {
                const int r = 32 * i + sr;
                const float* p = X + (size_t)(row0 + r) * D_DIM + dc * 64 + sg * 8;
                const float4 a = *(const float4*)p, b = *(const float4*)(p + 4);
                uint4 hi, lo; cvt_granule(a, b, hi, lo);
                const int o = r * 8 + (sg ^ (r & 7));
                fXh[o] = hi; fXl[o] = lo;
            }
#pragma unroll
            for (int i = 0; i < 4; ++i) {
                const int r = 32 * i + sr;
                const float* p = E + (size_t)(cs0 + ct * 128 + r) * D_DIM + dc * 64 + sg * 8;
                const float4 a = *(const float4*)p, b = *(const float4*)(p + 4);
                uint4 hi, lo; cvt_granule(a, b, hi, lo);
                const int o = r * 8 + (sg ^ (r & 7));
                fEh[o] = hi; fEl[o] = lo;
            }
            __syncthreads();

#pragma unroll
            for (int s = 0; s < 4; ++s) {
                const int gi = s * 2 + lh;
                f16x8 axh[2], axl[2], beh[2], bel[2];
#pragma unroll
                for (int ti = 0; ti < 2; ++ti) {
                    const int r = wr * 64 + ti * 32 + l31;
                    const int o = r * 8 + (gi ^ (r & 7));
                    axh[ti] = __builtin_bit_cast(f16x8, fXh[o]);
                    axl[ti] = __builtin_bit_cast(f16x8, fXl[o]);
                }
#pragma unroll
                for (int tj = 0; tj < 2; ++tj) {
                    const int c = wc * 64 + tj * 32 + l31;
                    const int o = c * 8 + (gi ^ (c & 7));
                    beh[tj] = __builtin_bit_cast(f16x8, fEh[o]);
                    bel[tj] = __builtin_bit_cast(f16x8, fEl[o]);
                }
#pragma unroll
                for (int ti = 0; ti < 2; ++ti)
#pragma unroll
                    for (int tj = 0; tj < 2; ++tj) {
                        acc[ti][tj] = MFMA32(axl[ti], beh[tj], acc[ti][tj]);
                        acc[ti][tj] = MFMA32(axh[ti], bel[tj], acc[ti][tj]);
                        acc[ti][tj] = MFMA32(axh[ti], beh[tj], acc[ti][tj]);
                    }
            }
        }

#pragma unroll
        for (int tj = 0; tj < 2; ++tj) {
            const int cloc = ct * 128 + wc * 64 + tj * 32 + l31;
            const float eb = fEsq[cloc];
            const int  code = cs0 + cloc;
#pragma unroll
            for (int ti = 0; ti < 2; ++ti)
#pragma unroll
                for (int r = 0; r < 16; ++r) {
                    const float dv = fmaf(-2.0f, acc[ti][tj][r], eb);
                    if (dv < best[ti][r]) { best[ti][r] = dv; bidx[ti][r] = code; }
                }
        }
    }

#pragma unroll
    for (int ti = 0; ti < 2; ++ti)
#pragma unroll
        for (int r = 0; r < 16; ++r) {
            float b = best[ti][r]; int bi = bidx[ti][r];
#pragma unroll
            for (int m = 16; m >= 1; m >>= 1) {
                const float ov = __shfl_xor(b, m, 32);
                const int   oi = __shfl_xor(bi, m, 32);
                if (ov < b || (ov == b && oi < bi)) { b = ov; bi = oi; }
            }
            if (l31 == 0) {
                const int row = row0 + wr * 64 + ti * 32 + (r & 3) + 8 * (r >> 2) + 4 * lh;
                const unsigned long long p =
                    ((unsigned long long)__float_as_uint(b) << 32) | (unsigned)bi;
                atomicMin(&packed[row], p);
            }
        }
}

// ---------------------------------------------------------------------------
__global__ void finish_kernel(const unsigned long long* __restrict__ packed,
                              int* __restrict__ out) {
    const int i = blockIdx.x * 256 + threadIdx.x;
    out[i] = (int)(unsigned)(packed[i] & 0xffffffffull);
}

// ---------------------------------------------------------------------------
extern "C" void kernel_launch(void* const* d_in, const int* in_sizes, int n_in,
                              void* d_out, int out_size, void* d_ws, size_t ws_size,
                              hipStream_t stream) {
    const float* X = (const float*)d_in[0];    // [32768, 256]
    const float* E = (const float*)d_in[1];    // [8192, 256]
    char* ws = (char*)d_ws;
    float* esqb = (float*)ws;                                        // 32 KB
    unsigned long long* packed = (unsigned long long*)(ws + 32768);  // 256 KB (fallback)
    int* out = (int*)d_out;

    const size_t base = 294912;                       // 32 KB + 256 KB, 16B-aligned
    const size_t szX  = (size_t)N_ROWS * D_DIM * 2;   // 16 MB per half
    const size_t szE  = (size_t)K_CODES * D_DIM * 2;  // 4 MB per half
    const size_t need = base + 2 * szX + 2 * szE;

    if (ws_size >= need) {
        uint4* Xh = (uint4*)(ws + base);
        uint4* Xl = (uint4*)(ws + base + szX);
        uint4* Eh = (uint4*)(ws + base + 2 * szX);
        uint4* El = (uint4*)(ws + base + 2 * szX + szE);
        prep_kernel<<<dim3(2368), dim3(256), 0, stream>>>(X, E, Xh, Xl, Eh, El, esqb);
        vq_mfma4_kernel<<<dim3(N_ROWS / 64), dim3(256), 0, stream>>>(
            Xh, Xl, Eh, El, esqb, out);
    } else {
        prologue_fb<<<dim3(2048), dim3(256), 0, stream>>>(E, esqb, packed);
        vq_mfma_fallback<<<dim3(N_ROWS / 128, 4), dim3(256), 0, stream>>>(X, E, esqb, packed);
        finish_kernel<<<dim3(N_ROWS / 256), dim3(256), 0, stream>>>(packed, out);
    }
}